// Round 16
// baseline (699.758 us; speedup 1.0000x reference)
//
#include <hip/hip_runtime.h>
#include <math.h>
#include <string.h>

#define NLAT 91
#define NLON 180
#define NCH  64
#define KSZ  25
#define NW   9
#define HALF 4
#define NB   2
#define NP2  32     // channel packs of 2
#define CGRP 16     // blocks over channel dim
#define PPB  2      // packs per block
#define THREADS 192
#define PCAP  32768
#define CCAP  2048
#define PTGT  224   // target points per balanced block
#define TCAP  288   // LDS table capacity (max cnt <= 255)
#define DCAP  256   // block-descriptor capacity
#define DLEN  40    // ints per descriptor

// blob layout (host-built in ctor, one pinned H2D per call)
#define DESC_OFF  0                               // 256*40*4 = 40960
#define PSIS_OFF  40960                           // float4 * np
#define BLOB_MAX  (PSIS_OFF + (size_t)PCAP * 16 + 64 + (size_t)PCAP * 4)

#ifndef M_PI
#define M_PI 3.14159265358979323846
#endif

typedef unsigned int u32;

// ---------------------------------------------------------------------------
// HOST (global ctor): per-POINT class tables, bit-compatible with numpy
// (glibc libm, exact IEEE order, contraction off). Validated rounds 2-15
// (absmax 1.5e-5). Points bucketed by (ring,sector) cell, then REORDERED
// into balanced blocks of ~PTGT points (class segments split evenly across
// S(t)=ceil(np_t/PTGT) sub-blocks; each block's points contiguous).
// Descriptor: {t, base, cnt, pad*5, loc[32]} (loc = local class boundaries).
// ---------------------------------------------------------------------------
static int build_tables(unsigned char* blob, size_t* offs_off_out, int* np_out)
{
#pragma clang fp contract(off)
    int*   desc = (int*)(blob + DESC_OFF);
    float* psis = (float*)(blob + PSIS_OFF);

    static double sth[NLAT], cth[NLAT], cphv[NLON], sphv[NLON];
    for (int t = 0; t < NLAT; t++) {
        double th = (M_PI * (double)t) / 90.0;
        sth[t] = sin(th); cth[t] = cos(th);
    }
    for (int q = 0; q < NLON; q++) {
        double ph = (2.0 * M_PI * (double)q) / 180.0;
        cphv[q] = cos(ph); sphv[q] = sin(ph);
    }
    const double cutoff = (4.0 * M_PI) / 90.0;
    const double dr     = cutoff / 4.0;
    const double dphi   = (2.0 * M_PI) / 6.0;

    static u32   coff[30][CCAP];
    static float cps[30][CCAP][4];
    static int   ccnt[30];
    // staging (pre-reorder) per-t stream
    static u32   soff[PCAP];
    static float spsi[PCAP][4];
    static int   clsOff[NLAT][31];
    static u32   roff[PCAP];   // reordered offsets

    int np = 0;
    for (int t = 0; t < NLAT; t++) {
        for (int c = 0; c < 30; c++) ccnt[c] = 0;
        for (int w = 0; w < NW; w++) {
            int ti_raw = t - HALF + w;
            int valid = (ti_raw >= 0) && (ti_raw < NLAT);
            int ti = ti_raw < 0 ? 0 : (ti_raw > NLAT - 1 ? NLAT - 1 : ti_raw);
            for (int dq = -89; dq <= 90; dq++) {
                int q = dq < 0 ? dq + NLON : dq;
                double t1 = sth[t] * sth[ti];
                double t2 = t1 * cphv[q];
                double t3 = cth[t] * cth[ti];
                double zz = t2 + t3;
                if (zz > 1.0) zz = 1.0;
                if (zz < -1.0) zz = -1.0;
                double r = acos(zz);
                if (!(valid && (r <= cutoff))) continue;
                double xx = (cth[t] * sth[ti]) * cphv[q] - sth[t] * cth[ti];
                double yy = sth[ti] * sphv[q];
                double phi = atan2(yy, xx);
                { double m = fmod(phi, 2.0 * M_PI); if (m < 0.0) m += 2.0 * M_PI; phi = m; }
                double quad = sth[ti] * (M_PI / 90.0) * ((2.0 * M_PI) / 180.0);

                int ir = (int)floor(r / dr);  if (ir > 4) ir = 4; if (ir < 0) ir = 0;
                int ip = (int)floor(phi / dphi); if (ip > 5) ip = 5; if (ip < 0) ip = 0;
                int ip1 = (ip + 1) % 6;

                double angL, angH;
                {
                    double a = (phi - ip * dphi) + M_PI;
                    double m = fmod(a, 2.0 * M_PI); if (m < 0.0) m += 2.0 * M_PI;
                    double dp = fabs(m - M_PI);
                    angL = fmax(0.0, 1.0 - dp / dphi);
                }
                {
                    double a = (phi - ip1 * dphi) + M_PI;
                    double m = fmod(a, 2.0 * M_PI); if (m < 0.0) m += 2.0 * M_PI;
                    double dp = fabs(m - M_PI);
                    angH = fmax(0.0, 1.0 - dp / dphi);
                }
                float s0 = 0.f, s1 = 0.f, s2 = 0.f, s3 = 0.f;
                if (ir == 0) {
                    double rad0 = fmax(0.0, 1.0 - r / dr);
                    double rad1 = fmax(0.0, 1.0 - fabs(r - dr) / dr);
                    s0 = (float)(rad0 * quad);
                    s1 = (float)((rad1 * angL) * quad);
                    s2 = (float)((rad1 * angH) * quad);
                } else if (ir == 4) {
                    double rad4 = fmax(0.0, 1.0 - fabs(r - 4.0 * dr) / dr);
                    s0 = (float)((rad4 * angL) * quad);
                    s1 = (float)((rad4 * angH) * quad);
                } else {
                    double radL = fmax(0.0, 1.0 - fabs(r - ir * dr) / dr);
                    double radH = fmax(0.0, 1.0 - fabs(r - (ir + 1) * dr) / dr);
                    s0 = (float)((radL * angL) * quad);
                    s1 = (float)((radL * angH) * quad);
                    s2 = (float)((radH * angL) * quad);
                    s3 = (float)((radH * angH) * quad);
                }
                if (s0 == 0.f && s1 == 0.f && s2 == 0.f && s3 == 0.f) continue;
                int cls = ir * 6 + ip;
                int n = ccnt[cls];
                if (n < CCAP) {
                    coff[cls][n] = (u32)(ti * 360 + dq + 90);
                    cps[cls][n][0] = s0; cps[cls][n][1] = s1;
                    cps[cls][n][2] = s2; cps[cls][n][3] = s3;
                    ccnt[cls] = n + 1;
                }
            }
        }
        for (int cls = 0; cls < 30; cls++) {
            clsOff[t][cls] = np;
            for (int i = 0; i < ccnt[cls] && np < PCAP; i++) {
                soff[np] = coff[cls][i];
                spsi[np][0] = cps[cls][i][0]; spsi[np][1] = cps[cls][i][1];
                spsi[np][2] = cps[cls][i][2]; spsi[np][3] = cps[cls][i][3];
                np++;
            }
        }
        clsOff[t][30] = np;
    }

    // balanced block build + point reorder
    int nBlk = 0, pos = 0;
    for (int t = 0; t < NLAT; t++) {
        int np_t = clsOff[t][30] - clsOff[t][0];
        int S = (np_t + PTGT - 1) / PTGT;
        if (S < 1) S = 1;
        for (int s = 0; s < S && nBlk < DCAP; s++) {
            int* D = desc + nBlk * DLEN;
            D[0] = t; D[1] = pos;
            int loc = 0;
            for (int j = 0; j < 30; j++) {
                int beg = clsOff[t][j];
                int len = clsOff[t][j + 1] - beg;
                int lo = beg + (int)((long long)len * s / S);
                int hi = beg + (int)((long long)len * (s + 1) / S);
                D[8 + j] = loc;
                for (int i = lo; i < hi; i++) {
                    roff[pos] = soff[i];
                    psis[4 * pos + 0] = spsi[i][0];
                    psis[4 * pos + 1] = spsi[i][1];
                    psis[4 * pos + 2] = spsi[i][2];
                    psis[4 * pos + 3] = spsi[i][3];
                    pos++; loc++;
                }
            }
            D[8 + 30] = loc;
            D[2] = loc;
            nBlk++;
        }
    }
    size_t offs_off = (PSIS_OFF + (size_t)pos * 16 + 63) & ~(size_t)63;
    memcpy(blob + offs_off, roff, (size_t)pos * 4);
    *offs_off_out = offs_off;
    *np_out = pos;
    return nBlk;
}

struct GInit {
    unsigned char* blob;
    int nBlk, np;
    size_t bytes, offs_off;
    GInit() {
        static unsigned char storage[BLOB_MAX];
        nBlk = build_tables(storage, &offs_off, &np);
        bytes = offs_off + (size_t)np * 4;
        unsigned char* p = nullptr;
        if (hipHostMalloc((void**)&p, bytes) == hipSuccess && p) {
            memcpy(p, storage, bytes);
            blob = p;
        } else {
            blob = storage;
        }
    }
};
static GInit g_init;

// ---------------------------------------------------------------------------
// pack x -> doubled 2-channel rows (u in [0,360), value at (u+90)%180).
// ---------------------------------------------------------------------------
__global__ __launch_bounds__(THREADS) void pack_x2(const float* __restrict__ x,
                                                   float2* __restrict__ xd)
{
    int t = blockIdx.x, cp2 = blockIdx.y, b = blockIdx.z;
    const float* x0 = x + ((size_t)(b * NCH + cp2 * 2) * NLAT + t) * NLON;
    const float* x1 = x0 + (size_t)NLAT * NLON;
    float2* dst = xd + ((size_t)(b * NP2 + cp2) * NLAT + t) * 360;
    for (int u = threadIdx.x; u < 360; u += THREADS) {
        int s = u + 90;
        if (s >= NLON) s -= NLON;
        if (s >= NLON) s -= NLON;
        dst[u] = make_float2(x0[s], x1[s]);
    }
}

__global__ void pack_w2(const float* __restrict__ wgt, float2* __restrict__ wt2)
{
    int i = blockIdx.x * blockDim.x + threadIdx.x;
    if (i >= NP2 * KSZ * NCH) return;
    int cp2 = i / (KSZ * NCH);
    int rem = i - cp2 * (KSZ * NCH);
    int k = rem / NCH;
    int o = rem - k * NCH;
    float2 v;
    v.x = wgt[((size_t)o * NCH + cp2 * 2 + 0) * KSZ + k];
    v.y = wgt[((size_t)o * NCH + cp2 * 2 + 1) * KSZ + k];
    wt2[i] = v;
}

// ---------------------------------------------------------------------------
// Stage-1 class body: table from LDS (in-order ds_read broadcasts), x from
// global (vmcnt), compile-time z targets.
// ---------------------------------------------------------------------------
template<int ROW, int IP>
__device__ __forceinline__ void runSegL(int iBeg, int iEnd,
    const u32* sOff, const float4* sPsi,
    const float2* __restrict__ xgb, int p,
    float (&z0)[2], float (&zA)[6][2], float (&zB)[6][2])
{
    constexpr int IP1 = (IP + 1) % 6;
#pragma unroll 4
    for (int i = iBeg; i < iEnd; ++i) {
        u32 off = sOff[i];           // ds_read_b32 (broadcast)
        float4 ps = sPsi[i];         // ds_read_b128 (broadcast)
        float2 xv = xgb[off + p];    // per-lane coalesced global
        if (ROW == 0) {
            z0[0] = fmaf(ps.x, xv.x, z0[0]);  z0[1] = fmaf(ps.x, xv.y, z0[1]);
            zB[IP][0] = fmaf(ps.y, xv.x, zB[IP][0]);   zB[IP][1] = fmaf(ps.y, xv.y, zB[IP][1]);
            zB[IP1][0] = fmaf(ps.z, xv.x, zB[IP1][0]); zB[IP1][1] = fmaf(ps.z, xv.y, zB[IP1][1]);
        } else if (ROW == 4) {
            zA[IP][0] = fmaf(ps.x, xv.x, zA[IP][0]);   zA[IP][1] = fmaf(ps.x, xv.y, zA[IP][1]);
            zA[IP1][0] = fmaf(ps.y, xv.x, zA[IP1][0]); zA[IP1][1] = fmaf(ps.y, xv.y, zA[IP1][1]);
        } else {
            zA[IP][0] = fmaf(ps.x, xv.x, zA[IP][0]);   zA[IP][1] = fmaf(ps.x, xv.y, zA[IP][1]);
            zA[IP1][0] = fmaf(ps.y, xv.x, zA[IP1][0]); zA[IP1][1] = fmaf(ps.y, xv.y, zA[IP1][1]);
            zB[IP][0] = fmaf(ps.z, xv.x, zB[IP][0]);   zB[IP][1] = fmaf(ps.z, xv.y, zB[IP][1]);
            zB[IP1][0] = fmaf(ps.w, xv.x, zB[IP1][0]); zB[IP1][1] = fmaf(ps.w, xv.y, zB[IP1][1]);
        }
    }
}

// ---------------------------------------------------------------------------
// Compact stage-2 flush (runtime j-loop, switch keeps z in registers).
// ---------------------------------------------------------------------------
__device__ __forceinline__ void flushRing2(float (&acc)[NCH],
    const float2* __restrict__ wt2cp, int kbase, const float (&zR)[6][2])
{
#pragma clang loop unroll(disable)
    for (int j = 0; j < 6; j++) {
        float zc0, zc1;
        switch (j) {
            case 0:  zc0 = zR[0][0]; zc1 = zR[0][1]; break;
            case 1:  zc0 = zR[1][0]; zc1 = zR[1][1]; break;
            case 2:  zc0 = zR[2][0]; zc1 = zR[2][1]; break;
            case 3:  zc0 = zR[3][0]; zc1 = zR[3][1]; break;
            case 4:  zc0 = zR[4][0]; zc1 = zR[4][1]; break;
            default: zc0 = zR[5][0]; zc1 = zR[5][1]; break;
        }
        const float2* wk = wt2cp + (size_t)(kbase + j) * NCH;
#pragma unroll
        for (int o = 0; o < NCH; o++) {
            float2 w2 = wk[o];
            acc[o] = fmaf(w2.y, zc1, fmaf(w2.x, zc0, acc[o]));
        }
    }
}

// ---------------------------------------------------------------------------
// Main fused kernel. Block = (balanced point-block, cg of 2 packs, b).
// Stage the block's point table (<=288 x 20B) into LDS once; ring walk with
// in-order ds broadcasts + per-lane global x; compact flush; atomics.
// ---------------------------------------------------------------------------
__global__ __launch_bounds__(THREADS, 4) void disco_fused(
    const float2* __restrict__ xg, const float2* __restrict__ wt2,
    const int* __restrict__ descG, const u32* __restrict__ offsG,
    const float4* __restrict__ psisG, float* __restrict__ out)
{
    int blk = blockIdx.x, cg = blockIdx.y, b = blockIdx.z;
    const int* D = descG + blk * DLEN;
    int t    = __builtin_amdgcn_readfirstlane(D[0]);
    int base = __builtin_amdgcn_readfirstlane(D[1]);
    int cnt  = __builtin_amdgcn_readfirstlane(D[2]);
    int tid = threadIdx.x;
    int p = tid < NLON ? tid : NLON - 1;
    bool act = tid < NLON;

    __shared__ u32    sOff[TCAP];
    __shared__ float4 sPsi[TCAP];
    for (int i = tid; i < cnt; i += THREADS) {
        sOff[i] = offsG[base + i];
        sPsi[i] = psisG[base + i];
    }
    __syncthreads();

    float acc[NCH];
#pragma unroll
    for (int o = 0; o < NCH; o++) acc[o] = 0.f;

#pragma clang loop unroll(disable)
    for (int pk = 0; pk < PPB; pk++) {
        int cp2 = cg * PPB + pk;
        const float2* xgb = xg + (size_t)(b * NP2 + cp2) * NLAT * 360;
        const float2* wt2cp = wt2 + (size_t)cp2 * KSZ * NCH;

        float z0[2] = {0.f, 0.f};
        float zA[6][2], zB[6][2];
#pragma unroll
        for (int j = 0; j < 6; j++) {
            zA[j][0] = 0.f; zA[j][1] = 0.f;
            zB[j][0] = 0.f; zB[j][1] = 0.f;
        }

#define SEG(ROW, IP) runSegL<ROW, IP>(D[8 + (ROW)*6 + (IP)], D[8 + (ROW)*6 + (IP) + 1], \
                                      sOff, sPsi, xgb, p, z0, zA, zB)
#define ROW6(ROW) SEG(ROW,0); SEG(ROW,1); SEG(ROW,2); SEG(ROW,3); SEG(ROW,4); SEG(ROW,5)
#define ROLL() { _Pragma("unroll") for (int j = 0; j < 6; j++) { \
                   zA[j][0] = zB[j][0]; zB[j][0] = 0.f; \
                   zA[j][1] = zB[j][1]; zB[j][1] = 0.f; } }

        ROW6(0);
        {   // flush k=0 from z0
            const float2* wk = wt2cp;
#pragma unroll
            for (int o = 0; o < NCH; o++) {
                float2 w2 = wk[o];
                acc[o] = fmaf(w2.y, z0[1], fmaf(w2.x, z0[0], acc[o]));
            }
        }
        ROLL();
        ROW6(1);
        flushRing2(acc, wt2cp, 1, zA);    // k 1..6
        ROLL();
        ROW6(2);
        flushRing2(acc, wt2cp, 7, zA);    // k 7..12
        ROLL();
        ROW6(3);
        flushRing2(acc, wt2cp, 13, zA);   // k 13..18
        ROLL();
        ROW6(4);
        flushRing2(acc, wt2cp, 19, zA);   // k 19..24
#undef SEG
#undef ROW6
#undef ROLL
    }

    if (act) {
        float* op = out + ((size_t)b * NCH * NLAT * NLON) + (size_t)t * NLON + p;
#pragma unroll
        for (int o = 0; o < NCH; o++)
            atomicAdd(op + (size_t)o * (NLAT * NLON), acc[o]);
    }
}

extern "C" void kernel_launch(void* const* d_in, const int* in_sizes, int n_in,
                              void* d_out, int out_size, void* d_ws, size_t ws_size,
                              hipStream_t stream)
{
    const float* x   = (const float*)d_in[0];
    const float* wgt = (const float*)d_in[1];
    char* ws = (char*)d_ws;

    size_t cur = 0;
    auto alloc = [&](size_t bytes) { size_t o = cur; cur = (cur + bytes + 255) & ~(size_t)255; return o; };
    size_t blob_off = alloc(BLOB_MAX);                                // ~0.7 MB
    size_t xd2_off  = alloc((size_t)NB * NP2 * NLAT * 360 * 8);       // 16.8 MB
    size_t wt2_off  = alloc((size_t)NP2 * KSZ * NCH * 8);             // 400 KB

    unsigned char* d_blob = (unsigned char*)(ws + blob_off);
    float2*        xd2    = (float2*)(ws + xd2_off);
    float2*        wt2    = (float2*)(ws + wt2_off);

    hipMemcpyAsync(d_blob, g_init.blob, g_init.bytes, hipMemcpyHostToDevice, stream);
    pack_x2<<<dim3(NLAT, NP2, NB), THREADS, 0, stream>>>(x, xd2);
    pack_w2<<<(NP2 * KSZ * NCH + 255) / 256, 256, 0, stream>>>(wgt, wt2);
    hipMemsetAsync(d_out, 0, (size_t)out_size * 4, stream);

    const int*    descD = (const int*)(d_blob + DESC_OFF);
    const u32*    offsD = (const u32*)(d_blob + g_init.offs_off);
    const float4* psisD = (const float4*)(d_blob + PSIS_OFF);

    disco_fused<<<dim3(g_init.nBlk, CGRP, NB), THREADS, 0, stream>>>(
        xd2, wt2, descD, offsD, psisD, (float*)d_out);
}

// Round 17
// 660.160 us; speedup vs baseline: 1.0600x; 1.0600x over previous
//
#include <hip/hip_runtime.h>
#include <math.h>
#include <string.h>

#define NLAT 91
#define NLON 180
#define NCH  64
#define KSZ  25
#define NW   9
#define HALF 4
#define NB   2
#define NP2  32     // channel packs of 2
#define CGRP 16     // blocks over channel dim
#define PPB  2      // packs per block
#define THREADS 192
#define PCAP  32768
#define CCAP  2048
#define SPLIT 320   // t's with more points than this get S=2 sub-blocks
#define TCAP  512   // LDS table capacity (max block cnt ~450)
#define DCAP  256
#define DLEN  40    // ints per descriptor: {t,base,cnt,slab,pad4,loc[31]}

// blob layout (host-built in ctor, one pinned H2D per call)
#define DESC_OFF  0                               // 256*40*4 = 40960
#define PSIS_OFF  40960
#define BLOB_MAX  (PSIS_OFF + (size_t)PCAP * 16 + 64 + (size_t)PCAP * 4)

#ifndef M_PI
#define M_PI 3.14159265358979323846
#endif

typedef unsigned int u32;

// ---------------------------------------------------------------------------
// HOST (global ctor): per-POINT class tables, bit-compatible with numpy
// (glibc libm, exact IEEE order, contraction off). Validated rounds 2-16
// (absmax 1.5e-5). Points bucketed by (ring,sector) cell; t's with >SPLIT
// points split into 2 sub-blocks (slab 0/1); descriptors sorted heavy-first.
// ---------------------------------------------------------------------------
static int build_tables(unsigned char* blob, size_t* offs_off_out, int* np_out)
{
#pragma clang fp contract(off)
    int*   desc = (int*)(blob + DESC_OFF);
    float* psis = (float*)(blob + PSIS_OFF);

    static double sth[NLAT], cth[NLAT], cphv[NLON], sphv[NLON];
    for (int t = 0; t < NLAT; t++) {
        double th = (M_PI * (double)t) / 90.0;
        sth[t] = sin(th); cth[t] = cos(th);
    }
    for (int q = 0; q < NLON; q++) {
        double ph = (2.0 * M_PI * (double)q) / 180.0;
        cphv[q] = cos(ph); sphv[q] = sin(ph);
    }
    const double cutoff = (4.0 * M_PI) / 90.0;
    const double dr     = cutoff / 4.0;
    const double dphi   = (2.0 * M_PI) / 6.0;

    static u32   coff[30][CCAP];
    static float cps[30][CCAP][4];
    static int   ccnt[30];
    static u32   soff[PCAP];
    static float spsi[PCAP][4];
    static int   clsOff[NLAT][31];
    static u32   roff[PCAP];
    static int   tmpD[DCAP][DLEN];

    int np = 0;
    for (int t = 0; t < NLAT; t++) {
        for (int c = 0; c < 30; c++) ccnt[c] = 0;
        for (int w = 0; w < NW; w++) {
            int ti_raw = t - HALF + w;
            int valid = (ti_raw >= 0) && (ti_raw < NLAT);
            int ti = ti_raw < 0 ? 0 : (ti_raw > NLAT - 1 ? NLAT - 1 : ti_raw);
            for (int dq = -89; dq <= 90; dq++) {
                int q = dq < 0 ? dq + NLON : dq;
                double t1 = sth[t] * sth[ti];
                double t2 = t1 * cphv[q];
                double t3 = cth[t] * cth[ti];
                double zz = t2 + t3;
                if (zz > 1.0) zz = 1.0;
                if (zz < -1.0) zz = -1.0;
                double r = acos(zz);
                if (!(valid && (r <= cutoff))) continue;
                double xx = (cth[t] * sth[ti]) * cphv[q] - sth[t] * cth[ti];
                double yy = sth[ti] * sphv[q];
                double phi = atan2(yy, xx);
                { double m = fmod(phi, 2.0 * M_PI); if (m < 0.0) m += 2.0 * M_PI; phi = m; }
                double quad = sth[ti] * (M_PI / 90.0) * ((2.0 * M_PI) / 180.0);

                int ir = (int)floor(r / dr);  if (ir > 4) ir = 4; if (ir < 0) ir = 0;
                int ip = (int)floor(phi / dphi); if (ip > 5) ip = 5; if (ip < 0) ip = 0;
                int ip1 = (ip + 1) % 6;

                double angL, angH;
                {
                    double a = (phi - ip * dphi) + M_PI;
                    double m = fmod(a, 2.0 * M_PI); if (m < 0.0) m += 2.0 * M_PI;
                    double dp = fabs(m - M_PI);
                    angL = fmax(0.0, 1.0 - dp / dphi);
                }
                {
                    double a = (phi - ip1 * dphi) + M_PI;
                    double m = fmod(a, 2.0 * M_PI); if (m < 0.0) m += 2.0 * M_PI;
                    double dp = fabs(m - M_PI);
                    angH = fmax(0.0, 1.0 - dp / dphi);
                }
                float s0 = 0.f, s1 = 0.f, s2 = 0.f, s3 = 0.f;
                if (ir == 0) {
                    double rad0 = fmax(0.0, 1.0 - r / dr);
                    double rad1 = fmax(0.0, 1.0 - fabs(r - dr) / dr);
                    s0 = (float)(rad0 * quad);
                    s1 = (float)((rad1 * angL) * quad);
                    s2 = (float)((rad1 * angH) * quad);
                } else if (ir == 4) {
                    double rad4 = fmax(0.0, 1.0 - fabs(r - 4.0 * dr) / dr);
                    s0 = (float)((rad4 * angL) * quad);
                    s1 = (float)((rad4 * angH) * quad);
                } else {
                    double radL = fmax(0.0, 1.0 - fabs(r - ir * dr) / dr);
                    double radH = fmax(0.0, 1.0 - fabs(r - (ir + 1) * dr) / dr);
                    s0 = (float)((radL * angL) * quad);
                    s1 = (float)((radL * angH) * quad);
                    s2 = (float)((radH * angL) * quad);
                    s3 = (float)((radH * angH) * quad);
                }
                if (s0 == 0.f && s1 == 0.f && s2 == 0.f && s3 == 0.f) continue;
                int cls = ir * 6 + ip;
                int n = ccnt[cls];
                if (n < CCAP) {
                    coff[cls][n] = (u32)(ti * 360 + dq + 90);
                    cps[cls][n][0] = s0; cps[cls][n][1] = s1;
                    cps[cls][n][2] = s2; cps[cls][n][3] = s3;
                    ccnt[cls] = n + 1;
                }
            }
        }
        for (int cls = 0; cls < 30; cls++) {
            clsOff[t][cls] = np;
            for (int i = 0; i < ccnt[cls] && np < PCAP; i++) {
                soff[np] = coff[cls][i];
                spsi[np][0] = cps[cls][i][0]; spsi[np][1] = cps[cls][i][1];
                spsi[np][2] = cps[cls][i][2]; spsi[np][3] = cps[cls][i][3];
                np++;
            }
        }
        clsOff[t][30] = np;
    }

    // balanced block build (S<=2), reorder points, slab = sub-block index
    int nBlk = 0, pos = 0;
    for (int t = 0; t < NLAT; t++) {
        int np_t = clsOff[t][30] - clsOff[t][0];
        int S = (np_t > SPLIT) ? 2 : 1;
        for (int s = 0; s < S && nBlk < DCAP; s++) {
            int* D = tmpD[nBlk];
            D[0] = t; D[1] = pos; D[3] = s;
            int loc = 0;
            for (int j = 0; j < 30; j++) {
                int beg = clsOff[t][j];
                int len = clsOff[t][j + 1] - beg;
                int lo = beg + (int)((long long)len * s / S);
                int hi = beg + (int)((long long)len * (s + 1) / S);
                D[8 + j] = loc;
                for (int i = lo; i < hi; i++) {
                    roff[pos] = soff[i];
                    psis[4 * pos + 0] = spsi[i][0];
                    psis[4 * pos + 1] = spsi[i][1];
                    psis[4 * pos + 2] = spsi[i][2];
                    psis[4 * pos + 3] = spsi[i][3];
                    pos++; loc++;
                }
            }
            D[8 + 30] = loc;
            D[2] = loc;
            nBlk++;
        }
    }
    // heavy-first: sort descriptors by cnt descending (selection sort)
    for (int i = 0; i < nBlk; i++) {
        int best = i;
        for (int j = i + 1; j < nBlk; j++)
            if (tmpD[j][2] > tmpD[best][2]) best = j;
        if (best != i)
            for (int k = 0; k < DLEN; k++) {
                int tv = tmpD[i][k]; tmpD[i][k] = tmpD[best][k]; tmpD[best][k] = tv;
            }
    }
    memcpy(desc, tmpD, (size_t)nBlk * DLEN * 4);

    size_t offs_off = (PSIS_OFF + (size_t)pos * 16 + 63) & ~(size_t)63;
    memcpy(blob + offs_off, roff, (size_t)pos * 4);
    *offs_off_out = offs_off;
    *np_out = pos;
    return nBlk;
}

struct GInit {
    unsigned char* blob;
    int nBlk, np;
    size_t bytes, offs_off;
    GInit() {
        static unsigned char storage[BLOB_MAX];
        nBlk = build_tables(storage, &offs_off, &np);
        bytes = offs_off + (size_t)np * 4;
        unsigned char* p = nullptr;
        if (hipHostMalloc((void**)&p, bytes) == hipSuccess && p) {
            memcpy(p, storage, bytes);
            blob = p;
        } else {
            blob = storage;
        }
    }
};
static GInit g_init;

// ---------------------------------------------------------------------------
// pack x -> doubled 2-channel rows (u in [0,360), value at (u+90)%180).
// ---------------------------------------------------------------------------
__global__ __launch_bounds__(THREADS) void pack_x2(const float* __restrict__ x,
                                                   float2* __restrict__ xd)
{
    int t = blockIdx.x, cp2 = blockIdx.y, b = blockIdx.z;
    const float* x0 = x + ((size_t)(b * NCH + cp2 * 2) * NLAT + t) * NLON;
    const float* x1 = x0 + (size_t)NLAT * NLON;
    float2* dst = xd + ((size_t)(b * NP2 + cp2) * NLAT + t) * 360;
    for (int u = threadIdx.x; u < 360; u += THREADS) {
        int s = u + 90;
        if (s >= NLON) s -= NLON;
        if (s >= NLON) s -= NLON;
        dst[u] = make_float2(x0[s], x1[s]);
    }
}

// ---------------------------------------------------------------------------
// weights, o-ROTATED per pack-group: wt2[(cp2*25+k)*64 + j] holds channel
// o = (j + 4*(cp2/PPB)) & 63. acc[j] in the kernel then maps to that o;
// different cg's write any given output line at different burst positions.
// ---------------------------------------------------------------------------
__global__ void pack_w2(const float* __restrict__ wgt, float2* __restrict__ wt2)
{
    int i = blockIdx.x * blockDim.x + threadIdx.x;
    if (i >= NP2 * KSZ * NCH) return;
    int cp2 = i / (KSZ * NCH);
    int rem = i - cp2 * (KSZ * NCH);
    int k = rem / NCH;
    int j = rem - k * NCH;
    int o = (j + 4 * (cp2 / PPB)) & 63;
    float2 v;
    v.x = wgt[((size_t)o * NCH + cp2 * 2 + 0) * KSZ + k];
    v.y = wgt[((size_t)o * NCH + cp2 * 2 + 1) * KSZ + k];
    wt2[i] = v;
}

// ---------------------------------------------------------------------------
// Stage-1 class body: table from LDS (in-order ds broadcasts), x from global
// (vmcnt, L1-resident), compile-time z targets.
// ---------------------------------------------------------------------------
template<int ROW, int IP>
__device__ __forceinline__ void runSegL(int iBeg, int iEnd,
    const u32* sOff, const float4* sPsi,
    const float2* __restrict__ xgb, int p,
    float (&z0)[2], float (&zA)[6][2], float (&zB)[6][2])
{
    constexpr int IP1 = (IP + 1) % 6;
#pragma unroll 4
    for (int i = iBeg; i < iEnd; ++i) {
        u32 off = sOff[i];
        float4 ps = sPsi[i];
        float2 xv = xgb[off + p];
        if (ROW == 0) {
            z0[0] = fmaf(ps.x, xv.x, z0[0]);  z0[1] = fmaf(ps.x, xv.y, z0[1]);
            zB[IP][0] = fmaf(ps.y, xv.x, zB[IP][0]);   zB[IP][1] = fmaf(ps.y, xv.y, zB[IP][1]);
            zB[IP1][0] = fmaf(ps.z, xv.x, zB[IP1][0]); zB[IP1][1] = fmaf(ps.z, xv.y, zB[IP1][1]);
        } else if (ROW == 4) {
            zA[IP][0] = fmaf(ps.x, xv.x, zA[IP][0]);   zA[IP][1] = fmaf(ps.x, xv.y, zA[IP][1]);
            zA[IP1][0] = fmaf(ps.y, xv.x, zA[IP1][0]); zA[IP1][1] = fmaf(ps.y, xv.y, zA[IP1][1]);
        } else {
            zA[IP][0] = fmaf(ps.x, xv.x, zA[IP][0]);   zA[IP][1] = fmaf(ps.x, xv.y, zA[IP][1]);
            zA[IP1][0] = fmaf(ps.y, xv.x, zA[IP1][0]); zA[IP1][1] = fmaf(ps.y, xv.y, zA[IP1][1]);
            zB[IP][0] = fmaf(ps.z, xv.x, zB[IP][0]);   zB[IP][1] = fmaf(ps.z, xv.y, zB[IP][1]);
            zB[IP1][0] = fmaf(ps.w, xv.x, zB[IP1][0]); zB[IP1][1] = fmaf(ps.w, xv.y, zB[IP1][1]);
        }
    }
}

// ---------------------------------------------------------------------------
// Compact stage-2 flush (runtime j-loop, switch keeps z in registers).
// ---------------------------------------------------------------------------
__device__ __forceinline__ void flushRing2(float (&acc)[NCH],
    const float2* __restrict__ wt2cp, int kbase, const float (&zR)[6][2])
{
#pragma clang loop unroll(disable)
    for (int j = 0; j < 6; j++) {
        float zc0, zc1;
        switch (j) {
            case 0:  zc0 = zR[0][0]; zc1 = zR[0][1]; break;
            case 1:  zc0 = zR[1][0]; zc1 = zR[1][1]; break;
            case 2:  zc0 = zR[2][0]; zc1 = zR[2][1]; break;
            case 3:  zc0 = zR[3][0]; zc1 = zR[3][1]; break;
            case 4:  zc0 = zR[4][0]; zc1 = zR[4][1]; break;
            default: zc0 = zR[5][0]; zc1 = zR[5][1]; break;
        }
        const float2* wk = wt2cp + (size_t)(kbase + j) * NCH;
#pragma unroll
        for (int o = 0; o < NCH; o++) {
            float2 w2 = wk[o];
            acc[o] = fmaf(w2.y, zc1, fmaf(w2.x, zc0, acc[o]));
        }
    }
}

// ---------------------------------------------------------------------------
// Main fused kernel. Block = (balanced point-block, cg, b). Stage the
// block's table into LDS; ring walk; compact flush; atomic epilogue into
// part[slab] with o-rotation (acc[j] <-> channel (j+4cg)&63).
// ---------------------------------------------------------------------------
__global__ __launch_bounds__(THREADS, 4) void disco_fused(
    const float2* __restrict__ xg, const float2* __restrict__ wt2,
    const int* __restrict__ descG, const u32* __restrict__ offsG,
    const float4* __restrict__ psisG, float* __restrict__ part)
{
    int blk = blockIdx.x, cg = blockIdx.y, b = blockIdx.z;
    const int* D = descG + blk * DLEN;
    int t    = __builtin_amdgcn_readfirstlane(D[0]);
    int base = __builtin_amdgcn_readfirstlane(D[1]);
    int cnt  = __builtin_amdgcn_readfirstlane(D[2]);
    int slab = __builtin_amdgcn_readfirstlane(D[3]);
    int tid = threadIdx.x;
    int p = tid < NLON ? tid : NLON - 1;
    bool act = tid < NLON;

    __shared__ u32    sOff[TCAP];
    __shared__ float4 sPsi[TCAP];
    for (int i = tid; i < cnt; i += THREADS) {
        sOff[i] = offsG[base + i];
        sPsi[i] = psisG[base + i];
    }
    __syncthreads();

    float acc[NCH];
#pragma unroll
    for (int o = 0; o < NCH; o++) acc[o] = 0.f;

#pragma clang loop unroll(disable)
    for (int pk = 0; pk < PPB; pk++) {
        int cp2 = cg * PPB + pk;
        const float2* xgb = xg + (size_t)(b * NP2 + cp2) * NLAT * 360;
        const float2* wt2cp = wt2 + (size_t)cp2 * KSZ * NCH;

        float z0[2] = {0.f, 0.f};
        float zA[6][2], zB[6][2];
#pragma unroll
        for (int j = 0; j < 6; j++) {
            zA[j][0] = 0.f; zA[j][1] = 0.f;
            zB[j][0] = 0.f; zB[j][1] = 0.f;
        }

#define SEG(ROW, IP) runSegL<ROW, IP>(D[8 + (ROW)*6 + (IP)], D[8 + (ROW)*6 + (IP) + 1], \
                                      sOff, sPsi, xgb, p, z0, zA, zB)
#define ROW6(ROW) SEG(ROW,0); SEG(ROW,1); SEG(ROW,2); SEG(ROW,3); SEG(ROW,4); SEG(ROW,5)
#define ROLL() { _Pragma("unroll") for (int j = 0; j < 6; j++) { \
                   zA[j][0] = zB[j][0]; zB[j][0] = 0.f; \
                   zA[j][1] = zB[j][1]; zB[j][1] = 0.f; } }

        ROW6(0);
        {   // flush k=0 from z0
            const float2* wk = wt2cp;
#pragma unroll
            for (int o = 0; o < NCH; o++) {
                float2 w2 = wk[o];
                acc[o] = fmaf(w2.y, z0[1], fmaf(w2.x, z0[0], acc[o]));
            }
        }
        ROLL();
        ROW6(1);
        flushRing2(acc, wt2cp, 1, zA);    // k 1..6
        ROLL();
        ROW6(2);
        flushRing2(acc, wt2cp, 7, zA);    // k 7..12
        ROLL();
        ROW6(3);
        flushRing2(acc, wt2cp, 13, zA);   // k 13..18
        ROLL();
        ROW6(4);
        flushRing2(acc, wt2cp, 19, zA);   // k 19..24
#undef SEG
#undef ROW6
#undef ROLL
    }

    if (act) {
        int rot = 4 * cg;
        float* op = part + ((size_t)slab * NB + b) * NCH * NLAT * NLON
                         + (size_t)t * NLON + p;
#pragma unroll
        for (int j = 0; j < NCH; j++) {
            int o = (j + rot) & 63;                  // runtime ADDRESS only
            atomicAdd(op + (size_t)o * (NLAT * NLON), acc[j]);
        }
    }
}

// ---------------------------------------------------------------------------
// out = part[0] + part[1]
// ---------------------------------------------------------------------------
__global__ void reduce_part(const float* __restrict__ part,
                            float* __restrict__ out, int n4)
{
    int i = blockIdx.x * blockDim.x + threadIdx.x;
    if (i >= n4) return;
    const float4* p4 = (const float4*)part;
    float4 a = p4[i];
    float4 b = p4[i + (size_t)n4];
    float4 r;
    r.x = a.x + b.x; r.y = a.y + b.y; r.z = a.z + b.z; r.w = a.w + b.w;
    ((float4*)out)[i] = r;
}

extern "C" void kernel_launch(void* const* d_in, const int* in_sizes, int n_in,
                              void* d_out, int out_size, void* d_ws, size_t ws_size,
                              hipStream_t stream)
{
    const float* x   = (const float*)d_in[0];
    const float* wgt = (const float*)d_in[1];
    char* ws = (char*)d_ws;

    size_t cur = 0;
    auto alloc = [&](size_t bytes) { size_t o = cur; cur = (cur + bytes + 255) & ~(size_t)255; return o; };
    size_t blob_off = alloc(BLOB_MAX);                                // ~0.7 MB
    size_t xd2_off  = alloc((size_t)NB * NP2 * NLAT * 360 * 8);       // 16.8 MB
    size_t wt2_off  = alloc((size_t)NP2 * KSZ * NCH * 8);             // 400 KB
    size_t part_off = alloc((size_t)2 * NB * NCH * NLAT * NLON * 4);  // 16.8 MB

    unsigned char* d_blob = (unsigned char*)(ws + blob_off);
    float2*        xd2    = (float2*)(ws + xd2_off);
    float2*        wt2    = (float2*)(ws + wt2_off);
    float*         part   = (float*)(ws + part_off);

    hipMemcpyAsync(d_blob, g_init.blob, g_init.bytes, hipMemcpyHostToDevice, stream);
    pack_x2<<<dim3(NLAT, NP2, NB), THREADS, 0, stream>>>(x, xd2);
    pack_w2<<<(NP2 * KSZ * NCH + 255) / 256, 256, 0, stream>>>(wgt, wt2);
    hipMemsetAsync(part, 0, (size_t)2 * NB * NCH * NLAT * NLON * 4, stream);

    const int*    descD = (const int*)(d_blob + DESC_OFF);
    const u32*    offsD = (const u32*)(d_blob + g_init.offs_off);
    const float4* psisD = (const float4*)(d_blob + PSIS_OFF);

    disco_fused<<<dim3(g_init.nBlk, CGRP, NB), THREADS, 0, stream>>>(
        xd2, wt2, descD, offsD, psisD, part);

    int n  = NB * NCH * NLAT * NLON;   // 2,096,640
    int n4 = n / 4;
    reduce_part<<<(n4 + 255) / 256, 256, 0, stream>>>(part, (float*)d_out, n4);
}